// Round 7
// baseline (317.051 us; speedup 1.0000x reference)
//
#include <hip/hip_runtime.h>
#include <hip/hip_bf16.h>

#define VOCAB 100000
#define EMB   300
#define BATCH 2048
#define SEQ   256
#define NBLK  1024           // proven co-resident at __launch_bounds__(256,4) (round 4)
#define NWAVE (NBLK * 4)     // 4096 waves
#define NQUAD (VOCAB / 4)    // 25000 row-quads
#define NGRP  32             // barrier groups
#define GRPSZ (NBLK / NGRP)  // 32 blocks per group

typedef float f4 __attribute__((ext_vector_type(4)));
typedef int   i4 __attribute__((ext_vector_type(4)));

// Fused kernel:
//   Phase 1: p[v] = dot(W_emb[v,:], fc_w)   (streams 120 MB, nt loads,
//            16 lanes/row, 4 rows/wave/iter, grid-stride over quads)
//   Barrier: hierarchical 2-level software barrier. Arrival = per-group
//            atomic counters; release = write-once FLAG lines (separate
//            cache lines from the counters). <=31 spinners per line at
//            s_sleep(8) (~0.21us) probe period -> ~0.15 G/s per line,
//            ~100x less single-line pressure than round 4's death spiral.
//   Phase 2: wave w < 2048 computes item w: int4 token load (preloaded
//            into registers BEFORE phase 1), 4 gathers, shfl reduce,
//            sigmoid, store.
__global__ void __launch_bounds__(256, 4) fused_kernel(
    const int* __restrict__ tokens, const int* __restrict__ lengths,
    const float* __restrict__ W, const float* __restrict__ fcw,
    const float* __restrict__ fcb, float* __restrict__ out,
    float* __restrict__ p, unsigned* __restrict__ bar) {
  const int tid  = threadIdx.x;
  const int lane = tid & 63;
  const int g    = lane >> 4;        // row within quad
  const int i    = lane & 15;        // lane within 16-lane group
  const int wave = ((blockIdx.x << 8) + tid) >> 6;   // 0..4095

  // ---- Preload phase-2 operands; pin them live so loads issue now and
  //      their latency hides under the phase-1 stream. ----
  i4  tok = {0, 0, 0, 0};
  int len = 1;
  if (wave < BATCH) {
    tok = ((const i4*)(tokens + (size_t)wave * SEQ))[lane];
    len = lengths[wave];
  }
  asm volatile("" :: "v"(tok[0]), "v"(tok[1]), "v"(tok[2]), "v"(tok[3]),
                     "v"(len));
  const float bias = fcb[0];

  const f4* fcw4 = (const f4*)fcw;
  const f4 zero = {0.f, 0.f, 0.f, 0.f};
  f4 w0 = fcw4[i];
  f4 w1 = fcw4[i + 16];
  f4 w2 = fcw4[i + 32];
  f4 w3 = fcw4[i + 48];
  f4 w4 = (i < 11) ? fcw4[i + 64] : zero;

  // ---- Phase 1: stream W_emb, write p ----
  for (int q = wave; q < NQUAD; q += NWAVE) {
    const int v = q * 4 + g;
    const f4* r = (const f4*)(W + (size_t)v * EMB);
    f4 a0 = __builtin_nontemporal_load(&r[i]);
    f4 a1 = __builtin_nontemporal_load(&r[i + 16]);
    f4 a2 = __builtin_nontemporal_load(&r[i + 32]);
    f4 a3 = __builtin_nontemporal_load(&r[i + 48]);
    f4 a4 = (i < 11) ? __builtin_nontemporal_load(&r[i + 64]) : zero;
    f4 s = a0 * w0 + a1 * w1 + a2 * w2 + a3 * w3 + a4 * w4;
    float acc = s.x + s.y + s.z + s.w;
    acc += __shfl_xor(acc, 8, 16);
    acc += __shfl_xor(acc, 4, 16);
    acc += __shfl_xor(acc, 2, 16);
    acc += __shfl_xor(acc, 1, 16);
    if (i == 0) p[v] = acc;
  }

  // ---- Hierarchical device-wide barrier ----
  // bar layout (uint indices, 64B-line-strided):
  //   [0]                glob_ctr
  //   [16]               glob_flag
  //   [32 + 16*grp]      grp_ctr[grp]
  //   [544 + 16*grp]     grp_flag[grp]     (544 = 32 + 16*NGRP)
  __threadfence();             // release: p stores visible agent-wide
  __syncthreads();
  if (tid == 0) {
    const int grp = blockIdx.x >> 5;                 // /GRPSZ
    unsigned* grp_ctr  = bar + 32 + (grp << 4);
    unsigned* grp_flag = bar + 544 + (grp << 4);
    if (atomicAdd(grp_ctr, 1u) == GRPSZ - 1) {       // last block of group
      if (atomicAdd(bar, 1u) == NGRP - 1) {          // last group overall
        __hip_atomic_store(bar + 16, 1u, __ATOMIC_RELEASE,
                           __HIP_MEMORY_SCOPE_AGENT);
      } else {
        while (!__hip_atomic_load(bar + 16, __ATOMIC_ACQUIRE,
                                  __HIP_MEMORY_SCOPE_AGENT))
          __builtin_amdgcn_s_sleep(8);
      }
      __hip_atomic_store(grp_flag, 1u, __ATOMIC_RELEASE,
                         __HIP_MEMORY_SCOPE_AGENT);
    } else {
      while (!__hip_atomic_load(grp_flag, __ATOMIC_ACQUIRE,
                                __HIP_MEMORY_SCOPE_AGENT))
        __builtin_amdgcn_s_sleep(8);
    }
  }
  __syncthreads();
  __threadfence();             // acquire: see all p stores

  // ---- Phase 2: wave w computes item w ----
  if (wave < BATCH) {
    const int base = lane * 4;
    float acc = 0.f;
    if (base + 0 < len) acc += p[tok[0]];
    if (base + 1 < len) acc += p[tok[1]];
    if (base + 2 < len) acc += p[tok[2]];
    if (base + 3 < len) acc += p[tok[3]];
    #pragma unroll
    for (int off = 32; off > 0; off >>= 1)
      acc += __shfl_down(acc, off, 64);
    if (lane == 0) {
      const float z = acc / (float)len + bias;
      out[wave] = 1.0f / (1.0f + expf(-z));
    }
  }
}

extern "C" void kernel_launch(void* const* d_in, const int* in_sizes, int n_in,
                              void* d_out, int out_size, void* d_ws, size_t ws_size,
                              hipStream_t stream) {
  const int*   tokens  = (const int*)d_in[0];    // [B, L]
  const int*   lengths = (const int*)d_in[1];    // [B]
  const float* W_emb   = (const float*)d_in[2];  // [VOCAB, EMB]
  const float* fc_w    = (const float*)d_in[3];  // [1, EMB]
  const float* fc_b    = (const float*)d_in[4];  // [1]
  float* out = (float*)d_out;                    // [B, 1]

  float*    p   = (float*)d_ws;                              // 400 KB table
  unsigned* bar = (unsigned*)((char*)d_ws + 401408);         // 1KB-aligned

  // Zero the barrier region (counters + flags) every call; 4352 B covers
  // glob_ctr/glob_flag + 32 grp_ctr lines + 32 grp_flag lines.
  hipMemsetAsync(bar, 0, 4352, stream);

  fused_kernel<<<NBLK, 256, 0, stream>>>(
      tokens, lengths, W_emb, fc_w, fc_b, out, p, bar);
}

// Round 8
// 27.067 us; speedup vs baseline: 11.7135x; 11.7135x over previous
//
#include <hip/hip_runtime.h>
#include <hip/hip_bf16.h>

#define VOCAB 100000
#define EMB   300
#define BATCH 2048
#define SEQ   256
#define NBLK1 1250   // 5000 waves x 20 rows (5 quads) = exactly 100000 rows

typedef float f4 __attribute__((ext_vector_type(4)));
typedef int   i4 __attribute__((ext_vector_type(4)));

// Kernel 1: p[v] = dot(W_emb[v, :], fc_w[:])  for v in [0, VOCAB)
// 16 lanes per row, 4 rows (one "quad") per wave-instruction-group, 5 quads
// per wave, 5000 waves -> zero tail, single co-resident dispatch pass
// (1250 blocks ~ 4.9 blocks/CU < capacity). Explicit ping-pong 2-deep
// pipeline keeps 10 f4 loads in flight with no register copies.
// Row = 75 float4 (16B-aligned, 300 % 4 == 0): lane i of group g reads f4
// idx {i, i+16, i+32, i+48} (+ i+64 if i<11) of its row. Segmented 4-step
// __shfl_xor width-16 reduce sums all 4 rows of a quad simultaneously.
__global__ void __launch_bounds__(256) vocab_dot_kernel(
    const float* __restrict__ W, const float* __restrict__ fcw,
    float* __restrict__ p) {
  const int lane = threadIdx.x & 63;
  const int g    = lane >> 4;        // row within quad
  const int i    = lane & 15;        // lane within 16-lane group
  const int wave = (blockIdx.x * 256 + threadIdx.x) >> 6;  // 0..4999
  const int vb   = wave * 20 + g;    // this lane-group's rows: vb + 4k

  const f4* fcw4 = (const f4*)fcw;
  const f4 zero = {0.f, 0.f, 0.f, 0.f};
  const f4 w0 = fcw4[i];
  const f4 w1 = fcw4[i + 16];
  const f4 w2 = fcw4[i + 32];
  const f4 w3 = fcw4[i + 48];
  const f4 w4 = (i < 11) ? fcw4[i + 64] : zero;

  f4 A0, A1, A2, A3, A4, B0, B1, B2, B3, B4;

#define LOADQ(R0, R1, R2, R3, R4, row)                                  \
  {                                                                     \
    const f4* r = (const f4*)(W + (size_t)(row) * EMB);                 \
    R0 = __builtin_nontemporal_load(&r[i]);                             \
    R1 = __builtin_nontemporal_load(&r[i + 16]);                        \
    R2 = __builtin_nontemporal_load(&r[i + 32]);                        \
    R3 = __builtin_nontemporal_load(&r[i + 48]);                        \
    R4 = (i < 11) ? __builtin_nontemporal_load(&r[i + 64]) : zero;      \
  }

#define COMPQ(R0, R1, R2, R3, R4, row)                                  \
  {                                                                     \
    f4 s = R0 * w0 + R1 * w1 + R2 * w2 + R3 * w3 + R4 * w4;             \
    float acc = s.x + s.y + s.z + s.w;                                  \
    acc += __shfl_xor(acc, 8, 16);                                      \
    acc += __shfl_xor(acc, 4, 16);                                      \
    acc += __shfl_xor(acc, 2, 16);                                      \
    acc += __shfl_xor(acc, 1, 16);                                      \
    if (i == 0) p[row] = acc;                                           \
  }

  LOADQ(A0, A1, A2, A3, A4, vb + 0);
  LOADQ(B0, B1, B2, B3, B4, vb + 4);
  COMPQ(A0, A1, A2, A3, A4, vb + 0);
  LOADQ(A0, A1, A2, A3, A4, vb + 8);
  COMPQ(B0, B1, B2, B3, B4, vb + 4);
  LOADQ(B0, B1, B2, B3, B4, vb + 12);
  COMPQ(A0, A1, A2, A3, A4, vb + 8);
  LOADQ(A0, A1, A2, A3, A4, vb + 16);
  COMPQ(B0, B1, B2, B3, B4, vb + 12);
  COMPQ(A0, A1, A2, A3, A4, vb + 16);

#undef LOADQ
#undef COMPQ
}

// Kernel 2: out[b] = sigmoid( (sum_{l<len} p[tok[b,l]]) / len + fc_b )
// One wave per item, 4 items per block. Lane reads int4 = 4 tokens (one
// coalesced 16B load covers the whole row of 256 tokens per wave), then 4
// independent gathers from the 400 KB p table (L2/L3-resident).
__global__ void __launch_bounds__(256) pool_sigmoid_kernel(
    const int* __restrict__ tokens, const int* __restrict__ lengths,
    const float* __restrict__ p, const float* __restrict__ fcb,
    float* __restrict__ out) {
  const int lane = threadIdx.x & 63;
  const int w    = threadIdx.x >> 6;
  const int b    = blockIdx.x * 4 + w;

  const int len = lengths[b];
  const i4 t = ((const i4*)(tokens + (size_t)b * SEQ))[lane];
  const int base = lane * 4;

  float acc = 0.f;
  if (base + 0 < len) acc += p[t[0]];
  if (base + 1 < len) acc += p[t[1]];
  if (base + 2 < len) acc += p[t[2]];
  if (base + 3 < len) acc += p[t[3]];

  #pragma unroll
  for (int off = 32; off > 0; off >>= 1)
    acc += __shfl_down(acc, off, 64);

  if (lane == 0) {
    const float z = acc / (float)len + fcb[0];
    out[b] = 1.0f / (1.0f + expf(-z));
  }
}

extern "C" void kernel_launch(void* const* d_in, const int* in_sizes, int n_in,
                              void* d_out, int out_size, void* d_ws, size_t ws_size,
                              hipStream_t stream) {
  const int*   tokens  = (const int*)d_in[0];    // [B, L]
  const int*   lengths = (const int*)d_in[1];    // [B]
  const float* W_emb   = (const float*)d_in[2];  // [VOCAB, EMB]
  const float* fc_w    = (const float*)d_in[3];  // [1, EMB]
  const float* fc_b    = (const float*)d_in[4];  // [1]
  float* out = (float*)d_out;                    // [B, 1]
  float* p   = (float*)d_ws;                     // VOCAB floats (400 KB)

  // Kernel 1: 1250 blocks x 256 threads = 5000 waves, 20 rows each, no tail,
  // single co-resident dispatch pass.
  vocab_dot_kernel<<<NBLK1, 256, 0, stream>>>(W_emb, fc_w, p);

  // Kernel 2: one wave per item, 4 items per block.
  pool_sigmoid_kernel<<<BATCH / 4, 256, 0, stream>>>(
      tokens, lengths, p, fc_b, out);
}